// Round 3
// baseline (226.869 us; speedup 1.0000x reference)
//
#include <hip/hip_runtime.h>

// UngroundedMicroProgram_3504693313604
// x: (S, 8, 6) fp32. Outputs concatenated fp32:
//   action_probs (2, S, 3)  -- both t-planes identical
//   p_values     (2, 28, S) -- plane r = i*4 + p*2 + k holds |x[s,0,p]-x[s,i+1,p]|
//
// R1: x4 coarsening -> dwordx4 stores. R2: drop nontemporal stores — NT
// bypassed L2 write-combining and interleaved the 138 MB write stream with
// the read-miss stream at DRAM (bus turnaround), capping BW at 3.3 TB/s.

typedef float v4f __attribute__((ext_vector_type(4)));

__global__ __launch_bounds__(256) void ump_kernel(
    const float* __restrict__ x,
    const float* __restrict__ action,
    const unsigned char* __restrict__ mask,   // bool array; byte-read ok
    const float* __restrict__ pred_bounds,
    float* __restrict__ out, int S)
{
    int t = blockIdx.x * blockDim.x + threadIdx.x;
    int s0 = t * 4;
    if (s0 >= S) return;

    const size_t Sl = (size_t)S;
    const float* row0 = x + (size_t)s0 * 48;

    const float lo0 = pred_bounds[0], hi0 = pred_bounds[1];
    const float lo1 = pred_bounds[2], hi1 = pred_bounds[3];

    // agent props for 4 consecutive rows
    float2 a[4];
#pragma unroll
    for (int r = 0; r < 4; ++r)
        a[r] = *(const float2*)(row0 + r * 48);

    bool enemy_all[4] = {true, true, true, true};
    bool any_sat[4]   = {false, false, false, false};

    float* pv = out + Sl * 6 + s0;   // p_values base for this thread

#pragma unroll
    for (int i = 0; i < 7; ++i) {
        float2 b[4];
#pragma unroll
        for (int r = 0; r < 4; ++r)
            b[r] = *(const float2*)(row0 + r * 48 + (i + 1) * 6);

        v4f d0, d1;
#pragma unroll
        for (int r = 0; r < 4; ++r) {
            float e0 = fabsf(a[r].x - b[r].x);
            float e1 = fabsf(a[r].y - b[r].y);
            d0[r] = e0;
            d1[r] = e1;
            enemy_all[r] = enemy_all[r] && (b[r].y > 0.8f);
            bool s0b = (e0 >= lo0) && (e0 <= hi0) && (e0 >= lo1) && (e0 <= hi1);
            bool s1b = (e1 >= lo0) && (e1 <= hi0) && (e1 >= lo1) && (e1 <= hi1);
            any_sat[r] = any_sat[r] || s0b || s1b;
        }

        // planes 4i..4i+3 (t=0) and +28 (t=1): k=0,1 duplicate each p
        float* q = pv + (size_t)(4 * i) * Sl;
        *(v4f*)(q)          = d0;
        *(v4f*)(q + Sl)     = d0;
        *(v4f*)(q + 2 * Sl) = d1;
        *(v4f*)(q + 3 * Sl) = d1;
        float* q2 = q + 28 * Sl;
        *(v4f*)(q2)          = d0;
        *(v4f*)(q2 + Sl)     = d0;
        *(v4f*)(q2 + 2 * Sl) = d1;
        *(v4f*)(q2 + 3 * Sl) = d1;
    }

    bool m0 = mask[0] != 0;
    bool m1 = mask[1] != 0;
    float an0 = action[0] / (action[0] + 1e-20f);
    float an1 = action[1] / (action[1] + 1e-20f);
    float an2 = action[2] / (action[2] + 1e-20f);

    // action_probs: 12 consecutive floats per t-plane (16B aligned)
    v4f ap[3];
#pragma unroll
    for (int r = 0; r < 4; ++r) {
        bool agent_exist = a[r].x > 0.8f;
        bool exist = (m0 == agent_exist) && (m1 == enemy_all[r]);
        bool sat   = exist && any_sat[r];
        ((float*)ap)[3 * r]     = sat ? an0 : 0.0f;
        ((float*)ap)[3 * r + 1] = sat ? an1 : 0.0f;
        ((float*)ap)[3 * r + 2] = sat ? an2 : 0.0f;
    }
    float* ap0 = out + (size_t)s0 * 3;
    float* ap1 = out + Sl * 3 + (size_t)s0 * 3;
#pragma unroll
    for (int j = 0; j < 3; ++j) {
        ((v4f*)ap0)[j] = ap[j];
        ((v4f*)ap1)[j] = ap[j];
    }
}

extern "C" void kernel_launch(void* const* d_in, const int* in_sizes, int n_in,
                              void* d_out, int out_size, void* d_ws, size_t ws_size,
                              hipStream_t stream) {
    const float*         x           = (const float*)d_in[0];
    const float*         action      = (const float*)d_in[1];
    const unsigned char* mask        = (const unsigned char*)d_in[2];
    const float*         pred_bounds = (const float*)d_in[3];
    float* out = (float*)d_out;

    const int S = in_sizes[0] / 48;  // 524288
    const int threads = S / 4;       // 4 rows per thread
    const int block = 256;
    const int grid = (threads + block - 1) / block;
    ump_kernel<<<grid, block, 0, stream>>>(x, action, mask, pred_bounds, out, S);
}

// Round 4
// 221.253 us; speedup vs baseline: 1.0254x; 1.0254x over previous
//
#include <hip/hip_runtime.h>

// UngroundedMicroProgram_3504693313604
// x: (S, 8, 6) fp32. Outputs concatenated fp32:
//   action_probs (2, S, 3)  -- both t-planes identical
//   p_values     (2, 28, S) -- plane r = t*28 + i*4 + p*2 + k holds |x[s,0,p]-x[s,i+1,p]|
//
// R3: keep x4-row coarsening (dwordx4 stores) but split the duplicate
// t-planes across block halves: sub = tid>>7 picks t-plane; both halves
// recompute d from the same rows (loads L1-shared). Doubles wave count
// (8 -> 16 waves/CU) while halving stores/thread. Theory: R2's regression
// vs R0 was work-starvation (2048 waves total), not store width.

typedef float v4f __attribute__((ext_vector_type(4)));

__global__ __launch_bounds__(256) void ump_kernel(
    const float* __restrict__ x,
    const float* __restrict__ action,
    const unsigned char* __restrict__ mask,   // bool array; byte-read ok
    const float* __restrict__ pred_bounds,
    float* __restrict__ out, int S)
{
    const int local = threadIdx.x & 127;
    const int sub   = threadIdx.x >> 7;                  // which t-plane copy
    const long g    = (long)blockIdx.x * 128 + local;    // 4-row group index
    const long s0   = g * 4;
    if (s0 >= S) return;

    const size_t Sl = (size_t)S;
    const float* row0 = x + (size_t)s0 * 48;

    const float lo0 = pred_bounds[0], hi0 = pred_bounds[1];
    const float lo1 = pred_bounds[2], hi1 = pred_bounds[3];

    // agent props for 4 consecutive rows
    float2 a[4];
#pragma unroll
    for (int r = 0; r < 4; ++r)
        a[r] = *(const float2*)(row0 + r * 48);

    bool enemy_all[4] = {true, true, true, true};
    bool any_sat[4]   = {false, false, false, false};

    // p_values base for this thread's t-plane
    float* pv = out + Sl * 6 + (size_t)sub * 28 * Sl + s0;

#pragma unroll
    for (int i = 0; i < 7; ++i) {
        float2 b[4];
#pragma unroll
        for (int r = 0; r < 4; ++r)
            b[r] = *(const float2*)(row0 + r * 48 + (i + 1) * 6);

        v4f d0, d1;
#pragma unroll
        for (int r = 0; r < 4; ++r) {
            float e0 = fabsf(a[r].x - b[r].x);
            float e1 = fabsf(a[r].y - b[r].y);
            d0[r] = e0;
            d1[r] = e1;
            enemy_all[r] = enemy_all[r] && (b[r].y > 0.8f);
            bool s0b = (e0 >= lo0) && (e0 <= hi0) && (e0 >= lo1) && (e0 <= hi1);
            bool s1b = (e1 >= lo0) && (e1 <= hi0) && (e1 >= lo1) && (e1 <= hi1);
            any_sat[r] = any_sat[r] || s0b || s1b;
        }

        // planes i*4 .. i*4+3 of this t-plane: k=0,1 duplicate each p
        float* q = pv + (size_t)(4 * i) * Sl;
        *(v4f*)(q)          = d0;
        *(v4f*)(q + Sl)     = d0;
        *(v4f*)(q + 2 * Sl) = d1;
        *(v4f*)(q + 3 * Sl) = d1;
    }

    bool m0 = mask[0] != 0;
    bool m1 = mask[1] != 0;
    float an0 = action[0] / (action[0] + 1e-20f);
    float an1 = action[1] / (action[1] + 1e-20f);
    float an2 = action[2] / (action[2] + 1e-20f);

    // action_probs for this t-plane: 12 consecutive floats (16B aligned: 48g bytes)
    v4f ap[3];
#pragma unroll
    for (int r = 0; r < 4; ++r) {
        bool agent_exist = a[r].x > 0.8f;
        bool exist = (m0 == agent_exist) && (m1 == enemy_all[r]);
        bool sat   = exist && any_sat[r];
        ((float*)ap)[3 * r]     = sat ? an0 : 0.0f;
        ((float*)ap)[3 * r + 1] = sat ? an1 : 0.0f;
        ((float*)ap)[3 * r + 2] = sat ? an2 : 0.0f;
    }
    float* apb = out + (size_t)sub * 3 * Sl + (size_t)s0 * 3;
#pragma unroll
    for (int j = 0; j < 3; ++j)
        ((v4f*)apb)[j] = ap[j];
}

extern "C" void kernel_launch(void* const* d_in, const int* in_sizes, int n_in,
                              void* d_out, int out_size, void* d_ws, size_t ws_size,
                              hipStream_t stream) {
    const float*         x           = (const float*)d_in[0];
    const float*         action      = (const float*)d_in[1];
    const unsigned char* mask        = (const unsigned char*)d_in[2];
    const float*         pred_bounds = (const float*)d_in[3];
    float* out = (float*)d_out;

    const int S = in_sizes[0] / 48;          // 524288
    const int groups = S / 4;                // 4-row groups
    const int block = 256;                   // 128 groups/block x 2 t-plane subs
    const int grid = (groups + 127) / 128;   // 1024 blocks
    ump_kernel<<<grid, block, 0, stream>>>(x, action, mask, pred_bounds, out, S);
}